// Round 15
// baseline (257.886 us; speedup 1.0000x reference)
//
#include <hip/hip_runtime.h>
#include <hip/hip_bf16.h>
#include <math.h>

// Problem constants (fixed by the reference)
#define TT 4096   // tokens = B*S
#define PP 8192   // pairs  = TT*K
#define DD 1024   // model dim
#define HH 2048   // expert hidden
#define EE 8      // experts
#define CC1 4096  // 2H (up-proj width)

typedef __attribute__((ext_vector_type(8))) short s16x8;
typedef __attribute__((ext_vector_type(4))) float f32x4;

// ---------------- workspace layout (bytes) ----------------
// down (64 MB, 4 K-split bf16 partials) REUSES the W1T region: w1t is dead after gemm1,
// and each call re-creates w1t via k_prep before gemm1 (deterministic, r11-proven).
#define W1T_OFF   0ull                                   // bf16 [E][4096][1024]  64 MB
#define DOWN_OFF  W1T_OFF                                // bf16 [4][P][1024]     64 MB (after gemm1)
#define W2T_OFF   (W1T_OFF + (size_t)EE*DD*CC1*2)        // bf16 [E][1024][2048]  32 MB
#define XB_OFF    (W2T_OFF + (size_t)EE*HH*DD*2)         // bf16 [T][1024]         8 MB
#define ABUF_OFF  (XB_OFF  + (size_t)TT*DD*2)            // bf16 [P][2048]        32 MB
#define META_OFF  (ABUF_OFF + (size_t)PP*HH*2)           // int meta[512] (2 KB)
#define PAIR_OFF  (META_OFF + 2048)                      // int [P]
#define POS_OFF   (PAIR_OFF + (size_t)PP*4)              // int [P]

#define VMCNT(N) asm volatile("s_waitcnt vmcnt(" #N ")" ::: "memory")
#define CFENCE() asm volatile("" ::: "memory")

__device__ __forceinline__ unsigned short f2bf(float f) {
  union { float f; unsigned u; } a; a.f = f;
  unsigned u = a.u;
  unsigned r = u + 0x7FFFu + ((u >> 16) & 1u);   // round-to-nearest-even
  return (unsigned short)(r >> 16);
}

__device__ __forceinline__ float bf2f(unsigned short s) {
  union { unsigned u; float f; } a; a.u = ((unsigned)s) << 16;
  return a.f;
}

// async global->LDS, 16B per lane; LDS dest must be wave-uniform base + lane*16
__device__ __forceinline__ void gload16(const void* g, void* l) {
  __builtin_amdgcn_global_load_lds(
      (const __attribute__((address_space(1))) void*)(uintptr_t)g,
      (__attribute__((address_space(3))) void*)(unsigned)(uintptr_t)l,
      16, 0, 0);
}

// ---------------- fused prep: route | x->bf16 | W1^T | W2^T in ONE launch ----------------
__device__ __forceinline__ void transpose_tile(const float* __restrict__ in,
                                               unsigned short* __restrict__ out,
                                               int R, int C, int bx, int by, int bz,
                                               float (*t)[65], int tid) {
  const size_t mbase = (size_t)bz * (size_t)R * (size_t)C;
  int c0 = bx * 64, r0 = by * 64;
#pragma unroll
  for (int i = 0; i < 4; ++i) {
    int ch = tid + i * 256;            // 1024 chunks of float4
    int row = ch >> 4, c4 = (ch & 15) * 4;
    float4 v = *reinterpret_cast<const float4*>(&in[mbase + (size_t)(r0 + row) * C + c0 + c4]);
    t[row][c4] = v.x; t[row][c4 + 1] = v.y; t[row][c4 + 2] = v.z; t[row][c4 + 3] = v.w;
  }
  __syncthreads();
#pragma unroll
  for (int i = 0; i < 4; ++i) {
    int ch = tid + i * 256;
    int c = ch >> 4, rb = (ch & 15) * 4;
    ushort4 o;
    o.x = f2bf(t[rb][c]); o.y = f2bf(t[rb + 1][c]);
    o.z = f2bf(t[rb + 2][c]); o.w = f2bf(t[rb + 3][c]);
    *reinterpret_cast<ushort4*>(&out[mbase + (size_t)(c0 + c) * R + r0 + rb]) = o;
  }
}

// meta[0]=ntiles256; meta[1..9]=offsets[0..8]; meta[10]=ntiles128;
// meta[16+2i]/(17+2i)=(e,q0) 256-tiles; meta[128+2i]/(129+2i)=(e,q0) 128-tiles
__global__ __launch_bounds__(256) void k_prep(
    const float* __restrict__ x, unsigned short* __restrict__ xb,
    const float* __restrict__ W1, unsigned short* __restrict__ w1t,
    const float* __restrict__ W2, unsigned short* __restrict__ w2t,
    const int* __restrict__ eidx, int* __restrict__ meta,
    int* __restrict__ plist, int* __restrict__ pos) {
  __shared__ float t[64][65];
  __shared__ int cnt[EE], off[EE + 1], cur[EE];
  const int b = blockIdx.x;
  const int tid = threadIdx.x;

  if (b == 0) {
    if (tid < EE) { cnt[tid] = 0; cur[tid] = 0; }
    __syncthreads();
    for (int p = tid; p < PP; p += blockDim.x) atomicAdd(&cnt[eidx[p]], 1);
    __syncthreads();
    if (tid == 0) {
      int s = 0;
      for (int e = 0; e < EE; ++e) { off[e] = s; s += cnt[e]; }
      off[EE] = s;
      int n256 = 0;
      for (int e = 0; e < EE; ++e)
        for (int r = 0; r < cnt[e]; r += 256) {
          meta[16 + 2*n256] = e; meta[17 + 2*n256] = off[e] + r; ++n256;
        }
      meta[0] = n256;
      int n128 = 0;
      for (int e = 0; e < EE; ++e)
        for (int r = 0; r < cnt[e]; r += 128) {
          meta[128 + 2*n128] = e; meta[129 + 2*n128] = off[e] + r; ++n128;
        }
      meta[10] = n128;
      for (int e = 0; e <= EE; ++e) meta[1 + e] = off[e];
    }
    __syncthreads();
    for (int p = tid; p < PP; p += blockDim.x) {
      int e = eidx[p];
      int q = off[e] + atomicAdd(&cur[e], 1);
      plist[q] = p;
      pos[p] = q;
    }
  } else if (b < 1 + 4096) {
    int i = (b - 1) * 256 + tid;                 // over TT*DD/4
    float4 v = reinterpret_cast<const float4*>(x)[i];
    ushort4 o;
    o.x = f2bf(v.x); o.y = f2bf(v.y); o.z = f2bf(v.z); o.w = f2bf(v.w);
    reinterpret_cast<ushort4*>(xb)[i] = o;
  } else if (b < 1 + 4096 + 8192) {
    int flat = b - (1 + 4096);
    transpose_tile(W1, w1t, DD, CC1, flat & 63, (flat >> 6) & 15, flat >> 10, t, tid);
  } else {
    int flat = b - (1 + 4096 + 8192);
    transpose_tile(W2, w2t, HH, DD, flat & 15, (flat >> 4) & 31, flat >> 9, t, tid);
  }
}

// ---------------- GEMM1: up = x @ W1[e], fused GLU + gate, bf16 out (sorted order) ----------
// 256x128 tile, BK=64, 8 waves (4Mx2N), depth-2 prefetch (3 LDS buffers), counted
// vmcnt(6) + raw s_barrier, T2 XOR-swizzle, K-loop fully unrolled w/ const indices.
// grid: (40 row-tiles, 32 col-tiles); block 512   [round-13 proven, ~120 us]
__global__ __launch_bounds__(512) void k_gemm1(
    const unsigned short* __restrict__ xb,     // [T][1024] bf16
    const unsigned short* __restrict__ w1t,    // [E][4096][1024] bf16 ([col][k])
    const float* __restrict__ gates,           // [P] f32
    const int* __restrict__ meta,
    const int* __restrict__ plist,
    unsigned short* __restrict__ abuf)         // [P][2048] bf16
{
  const int nt = meta[0];
  const int tb = blockIdx.x;
  if (tb >= nt) return;
  const int e  = meta[16 + 2*tb];
  const int q0 = meta[17 + 2*tb];
  const int nrows = min(256, meta[2 + e] - q0);
  const int c0 = blockIdx.y * 64;              // h-col base

  __shared__ unsigned short As[3][256 * 64];   // 96 KB
  __shared__ unsigned short Bs[3][128 * 64];   // 48 KB

  const int tid = threadIdx.x;                 // 0..511
  const int wave = tid >> 6, lane = tid & 63;
  const int l15 = lane & 15, l4 = lane >> 4;
  const int wr = wave >> 1, wc = wave & 1;     // 4M x 2N wave grid

  const unsigned short* w1e = w1t + (size_t)e * CC1 * DD;

  const unsigned short* aga[4];
  const unsigned short* bga[2];
#pragma unroll
  for (int i = 0; i < 4; ++i) {
    int c = tid + i * 512;                     // 0..2047
    int row = c >> 3;                          // 0..255
    int ko = ((c & 7) ^ (row & 7)) * 8;
    int r = row < nrows ? row : 0;
    int p = plist[q0 + r];
    aga[i] = xb + (size_t)(p >> 1) * DD + ko;
  }
#pragma unroll
  for (int i = 0; i < 2; ++i) {
    int c = tid + i * 512;                     // 0..1023
    int row = c >> 3;                          // 0..127
    int ko = ((c & 7) ^ (row & 7)) * 8;
    int u = row & 63, wcq = row >> 6;
    int col = (u < 32) ? (c0 + wcq * 32 + u) : (HH + c0 + wcq * 32 + (u - 32));
    bga[i] = w1e + (size_t)col * DD + ko;
  }

  f32x4 acc[4][4];
#pragma unroll
  for (int a = 0; a < 4; ++a)
#pragma unroll
    for (int b = 0; b < 4; ++b) acc[a][b] = (f32x4)0.0f;

  auto stage = [&](int kk, unsigned short* pa, unsigned short* pb) {
#pragma unroll
    for (int i = 0; i < 4; ++i) gload16(aga[i] + kk, pa + (tid + i * 512) * 8);
#pragma unroll
    for (int i = 0; i < 2; ++i) gload16(bga[i] + kk, pb + (tid + i * 512) * 8);
  };

  auto compute_tile = [&](const unsigned short* sa, const unsigned short* sb) {
    const char* A8 = (const char*)sa;
    const char* B8 = (const char*)sb;
#pragma unroll
    for (int ks = 0; ks < 2; ++ks) {
      s16x8 af[4], bfr[4];
#pragma unroll
      for (int rf = 0; rf < 4; ++rf) {
        int row = wr * 64 + rf * 16 + l15;
        af[rf] = *(const s16x8*)(A8 + ((row * 128 + ks * 64 + l4 * 16) ^ ((row & 7) << 4)));
      }
#pragma unroll
      for (int cf = 0; cf < 4; ++cf) {
        int row = wc * 64 + cf * 16 + l15;
        bfr[cf] = *(const s16x8*)(B8 + ((row * 128 + ks * 64 + l4 * 16) ^ ((row & 7) << 4)));
      }
#pragma unroll
      for (int rf = 0; rf < 4; ++rf)
#pragma unroll
        for (int cf = 0; cf < 4; ++cf)
          acc[rf][cf] = __builtin_amdgcn_mfma_f32_16x16x32_bf16(af[rf], bfr[cf], acc[rf][cf], 0, 0, 0);
    }
  };

  stage(0, As[0], Bs[0]);
  stage(64, As[1], Bs[1]);
  VMCNT(6);                                    // tile 0 landed; tile 1 may fly
  __builtin_amdgcn_s_barrier();
  CFENCE();

#pragma unroll
  for (int kt = 0; kt < 14; ++kt) {            // DD/64 - 2; fully unrolled, const indices
    stage((kt + 2) * 64, As[(kt + 2) % 3], Bs[(kt + 2) % 3]);
    compute_tile(As[kt % 3], Bs[kt % 3]);
    VMCNT(6);                                  // all but newest K-tile landed
    __builtin_amdgcn_s_barrier();
    CFENCE();
  }
  compute_tile(As[14 % 3], Bs[14 % 3]);        // tile NT-2
  VMCNT(0);
  __builtin_amdgcn_s_barrier();
  CFENCE();
  compute_tile(As[15 % 3], Bs[15 % 3]);        // tile NT-1

  // Epilogue: a = gelu_exact(h) * (g+1) * gate, bf16.
#pragma unroll
  for (int rf = 0; rf < 4; ++rf) {
#pragma unroll
    for (int i = 0; i < 4; ++i) {
      int r = wr * 64 + rf * 16 + l4 * 4 + i;
      if (r < nrows) {
        int q = q0 + r;
        float gt = gates[plist[q]];
        unsigned short* orow = abuf + (size_t)q * HH + c0 + wc * 32 + l15;
#pragma unroll
        for (int cf = 0; cf < 2; ++cf) {
          float hv = acc[rf][cf][i];
          float gv = acc[rf][cf + 2][i];
          float av = 0.5f * hv * (1.0f + erff(hv * 0.70710678118654752f)) * (gv + 1.0f) * gt;
          orow[cf * 16] = f2bf(av);
        }
      }
    }
  }
}

// ---------------- GEMM2: down_z = a @ W2[e][kz:kz+512], bf16 partials (K-split 4) ---------
// m97-shape: 128x128 tile, 4 waves (2x2), SINGLE-buffer 32 KB LDS -> ~5 blocks/CU;
// barrier drains hidden by co-resident blocks (m114). Both-sides XOR swizzle; NT=8
// fully unrolled. grid: (72 x 128-row tiles, 8 col-tiles, 4 K-quarters); block 256.
__global__ __launch_bounds__(256) void k_gemm2(
    const unsigned short* __restrict__ abuf,   // [P][2048] bf16
    const unsigned short* __restrict__ w2t,    // [E][1024][2048] bf16 ([col][k])
    const int* __restrict__ meta,
    unsigned short* __restrict__ down)         // [4][P][1024] bf16
{
  const int nt = meta[10];
  const int tb = blockIdx.x;
  if (tb >= nt) return;
  const int e  = meta[128 + 2*tb];
  const int q0 = meta[129 + 2*tb];
  const int nrows = min(128, meta[2 + e] - q0);
  const int c0 = blockIdx.y * 128;
  const int kz = blockIdx.z * (HH / 4);        // K-quarter base (512)

  __shared__ unsigned short As[128 * 64];      // 16 KB
  __shared__ unsigned short Bs[128 * 64];      // 16 KB

  const int tid = threadIdx.x;                 // 0..255
  const int wave = tid >> 6, lane = tid & 63;
  const int l15 = lane & 15, l4 = lane >> 4;
  const int wr = wave >> 1, wc = wave & 1;     // 2M x 2N wave grid (64x64 per wave)

  const unsigned short* w2e = w2t + (size_t)e * DD * HH;

  const unsigned short* aga[4];
  const unsigned short* bga[4];
#pragma unroll
  for (int i = 0; i < 4; ++i) {
    int c = tid + i * 256;                     // 0..1023
    int row = c >> 3;                          // 0..127
    int ko = ((c & 7) ^ (row & 7)) * 8;
    int r = row < nrows ? row : 0;
    aga[i] = abuf + (size_t)(q0 + r) * HH + kz + ko;
    bga[i] = w2e + (size_t)(c0 + row) * HH + kz + ko;
  }

  f32x4 acc[4][4];
#pragma unroll
  for (int a = 0; a < 4; ++a)
#pragma unroll
    for (int b = 0; b < 4; ++b) acc[a][b] = (f32x4)0.0f;

  auto stage = [&](int kk) {
#pragma unroll
    for (int i = 0; i < 4; ++i) gload16(aga[i] + kk, As + (tid + i * 256) * 8);
#pragma unroll
    for (int i = 0; i < 4; ++i) gload16(bga[i] + kk, Bs + (tid + i * 256) * 8);
  };

  auto compute_tile = [&]() {
    const char* A8 = (const char*)As;
    const char* B8 = (const char*)Bs;
#pragma unroll
    for (int ks = 0; ks < 2; ++ks) {
      s16x8 af[4], bfr[4];
#pragma unroll
      for (int rf = 0; rf < 4; ++rf) {
        int row = wr * 64 + rf * 16 + l15;
        af[rf] = *(const s16x8*)(A8 + ((row * 128 + ks * 64 + l4 * 16) ^ ((row & 7) << 4)));
      }
#pragma unroll
      for (int cf = 0; cf < 4; ++cf) {
        int row = wc * 64 + cf * 16 + l15;
        bfr[cf] = *(const s16x8*)(B8 + ((row * 128 + ks * 64 + l4 * 16) ^ ((row & 7) << 4)));
      }
#pragma unroll
      for (int rf = 0; rf < 4; ++rf)
#pragma unroll
        for (int cf = 0; cf < 4; ++cf)
          acc[rf][cf] = __builtin_amdgcn_mfma_f32_16x16x32_bf16(af[rf], bfr[cf], acc[rf][cf], 0, 0, 0);
    }
  };

#pragma unroll
  for (int kt = 0; kt < 8; ++kt) {             // (HH/4)/64; single-buffer m97 loop
    stage(kt * 64);
    __syncthreads();                           // loads landed & visible
    compute_tile();
    if (kt < 7) __syncthreads();               // all waves done reading before overwrite
  }

  unsigned short* dz = down + (size_t)blockIdx.z * PP * DD;
#pragma unroll
  for (int rf = 0; rf < 4; ++rf) {
#pragma unroll
    for (int i = 0; i < 4; ++i) {
      int r = wr * 64 + rf * 16 + l4 * 4 + i;
      if (r < nrows) {
        int q = q0 + r;
        unsigned short* orow = dz + (size_t)q * DD + c0 + wc * 64 + l15;
#pragma unroll
        for (int cf = 0; cf < 4; ++cf) orow[cf * 16] = f2bf(acc[rf][cf][i]);
      }
    }
  }
}

// ---------------- combine: y[t] = sum over {pair a,b} x {K-quarter 0..3} of bf16 partials --
__global__ void k_combine(const unsigned short* __restrict__ down, const int* __restrict__ pos,
                          float* __restrict__ y) {
  int i = blockIdx.x * blockDim.x + threadIdx.x;  // over TT*DD/8
  if (i >= TT * DD / 8) return;
  int t = i >> 7;            // DD/8 = 128 chunks per row
  int c8 = (i & 127) * 8;
  int qa = pos[2 * t], qb = pos[2 * t + 1];
  float o[8];
#pragma unroll
  for (int j = 0; j < 8; ++j) o[j] = 0.0f;
#pragma unroll
  for (int z = 0; z < 4; ++z) {
    const unsigned short* dz = down + (size_t)z * PP * DD;
    s16x8 va = *reinterpret_cast<const s16x8*>(dz + (size_t)qa * DD + c8);
    s16x8 vb = *reinterpret_cast<const s16x8*>(dz + (size_t)qb * DD + c8);
#pragma unroll
    for (int j = 0; j < 8; ++j)
      o[j] += bf2f((unsigned short)va[j]) + bf2f((unsigned short)vb[j]);
  }
  float4* yo = reinterpret_cast<float4*>(y + (size_t)t * DD + c8);
  yo[0] = (float4){o[0], o[1], o[2], o[3]};
  yo[1] = (float4){o[4], o[5], o[6], o[7]};
}

extern "C" void kernel_launch(void* const* d_in, const int* in_sizes, int n_in,
                              void* d_out, int out_size, void* d_ws, size_t ws_size,
                              hipStream_t stream) {
  const float* x  = (const float*)d_in[0];
  const float* ep = (const float*)d_in[1];
  const int*   ei = (const int*)d_in[2];
  const float* W1 = (const float*)d_in[3];
  const float* W2 = (const float*)d_in[4];
  float* y = (float*)d_out;
  char* ws = (char*)d_ws;

  unsigned short* w1t = (unsigned short*)(ws + W1T_OFF);
  unsigned short* w2t = (unsigned short*)(ws + W2T_OFF);
  unsigned short* xb  = (unsigned short*)(ws + XB_OFF);
  unsigned short* ab  = (unsigned short*)(ws + ABUF_OFF);
  unsigned short* down = (unsigned short*)(ws + DOWN_OFF);  // reuses W1T region
  int* meta   = (int*)(ws + META_OFF);
  int* plist  = (int*)(ws + PAIR_OFF);
  int* pos    = (int*)(ws + POS_OFF);

  // fused prep: 1 (route) + 4096 (cvt_x) + 8192 (W1^T) + 4096 (W2^T) blocks
  hipLaunchKernelGGL(k_prep, dim3(1 + 4096 + 8192 + 4096), dim3(256), 0, stream,
                     x, xb, W1, w1t, W2, w2t, ei, meta, plist, pos);
  hipLaunchKernelGGL(k_gemm1, dim3(40, 32), dim3(512), 0, stream,
                     xb, w1t, ep, meta, plist, ab);
  hipLaunchKernelGGL(k_gemm2, dim3(72, 8, 4), dim3(256), 0, stream,
                     ab, w2t, meta, down);
  hipLaunchKernelGGL(k_combine, dim3(TT * DD / 8 / 256), dim3(256), 0, stream,
                     down, pos, y);
}

// Round 16
// 243.738 us; speedup vs baseline: 1.0580x; 1.0580x over previous
//
#include <hip/hip_runtime.h>
#include <hip/hip_bf16.h>
#include <math.h>

// Problem constants (fixed by the reference)
#define TT 4096   // tokens = B*S
#define PP 8192   // pairs  = TT*K
#define DD 1024   // model dim
#define HH 2048   // expert hidden
#define EE 8      // experts
#define CC1 4096  // 2H (up-proj width)

typedef __attribute__((ext_vector_type(8))) short s16x8;
typedef __attribute__((ext_vector_type(4))) float f32x4;

// ---------------- workspace layout (bytes) ----------------
#define W1T_OFF   0ull                                   // bf16 [E][4096][1024]  64 MB
#define W2T_OFF   (W1T_OFF + (size_t)EE*DD*CC1*2)        // bf16 [E][1024][2048]  32 MB
#define XB_OFF    (W2T_OFF + (size_t)EE*HH*DD*2)         // bf16 [T][1024]         8 MB
#define ABUF_OFF  (XB_OFF  + (size_t)TT*DD*2)            // bf16 [P][2048]        32 MB
#define DOWN_OFF  (ABUF_OFF + (size_t)PP*HH*2)           // bf16 [2][P][1024]     32 MB
#define META_OFF  (DOWN_OFF + (size_t)2*PP*DD*2)         // int meta[512] (2 KB)
#define PAIR_OFF  (META_OFF + 2048)                      // int [P]
#define POS_OFF   (PAIR_OFF + (size_t)PP*4)              // int [P]

#define VMCNT(N) asm volatile("s_waitcnt vmcnt(" #N ")" ::: "memory")
#define CFENCE() asm volatile("" ::: "memory")

__device__ __forceinline__ unsigned short f2bf(float f) {
  union { float f; unsigned u; } a; a.f = f;
  unsigned u = a.u;
  unsigned r = u + 0x7FFFu + ((u >> 16) & 1u);   // round-to-nearest-even
  return (unsigned short)(r >> 16);
}

__device__ __forceinline__ float bf2f(unsigned short s) {
  union { unsigned u; float f; } a; a.u = ((unsigned)s) << 16;
  return a.f;
}

// async global->LDS, 16B per lane; LDS dest must be wave-uniform base + lane*16
__device__ __forceinline__ void gload16(const void* g, void* l) {
  __builtin_amdgcn_global_load_lds(
      (const __attribute__((address_space(1))) void*)(uintptr_t)g,
      (__attribute__((address_space(3))) void*)(unsigned)(uintptr_t)l,
      16, 0, 0);
}

// ---------------- fused prep: route | x->bf16 | W1^T | W2^T in ONE launch ----------------
// block 0: route; [1,4097): cvt_x; [4097,12289): W1 transpose; [12289,16385): W2 transpose.
// Saves 3 launch gaps and lets the three BW-bound streams fill each other's tails.
__device__ __forceinline__ void transpose_tile(const float* __restrict__ in,
                                               unsigned short* __restrict__ out,
                                               int R, int C, int bx, int by, int bz,
                                               float (*t)[65], int tid) {
  const size_t mbase = (size_t)bz * (size_t)R * (size_t)C;
  int c0 = bx * 64, r0 = by * 64;
#pragma unroll
  for (int i = 0; i < 4; ++i) {
    int ch = tid + i * 256;            // 1024 chunks of float4
    int row = ch >> 4, c4 = (ch & 15) * 4;
    float4 v = *reinterpret_cast<const float4*>(&in[mbase + (size_t)(r0 + row) * C + c0 + c4]);
    t[row][c4] = v.x; t[row][c4 + 1] = v.y; t[row][c4 + 2] = v.z; t[row][c4 + 3] = v.w;
  }
  __syncthreads();
#pragma unroll
  for (int i = 0; i < 4; ++i) {
    int ch = tid + i * 256;
    int c = ch >> 4, rb = (ch & 15) * 4;
    ushort4 o;
    o.x = f2bf(t[rb][c]); o.y = f2bf(t[rb + 1][c]);
    o.z = f2bf(t[rb + 2][c]); o.w = f2bf(t[rb + 3][c]);
    *reinterpret_cast<ushort4*>(&out[mbase + (size_t)(c0 + c) * R + r0 + rb]) = o;
  }
}

__global__ __launch_bounds__(256) void k_prep(
    const float* __restrict__ x, unsigned short* __restrict__ xb,
    const float* __restrict__ W1, unsigned short* __restrict__ w1t,
    const float* __restrict__ W2, unsigned short* __restrict__ w2t,
    const int* __restrict__ eidx, int* __restrict__ meta,
    int* __restrict__ plist, int* __restrict__ pos) {
  __shared__ float t[64][65];
  __shared__ int cnt[EE], off[EE + 1], cur[EE];
  const int b = blockIdx.x;
  const int tid = threadIdx.x;

  if (b == 0) {
    // ---- route: bucket pairs by expert, 256-row tile list, inverse perm ----
    if (tid < EE) { cnt[tid] = 0; cur[tid] = 0; }
    __syncthreads();
    for (int p = tid; p < PP; p += blockDim.x) atomicAdd(&cnt[eidx[p]], 1);
    __syncthreads();
    if (tid == 0) {
      int s = 0;
      for (int e = 0; e < EE; ++e) { off[e] = s; s += cnt[e]; }
      off[EE] = s;
      int n256 = 0;
      for (int e = 0; e < EE; ++e)
        for (int r = 0; r < cnt[e]; r += 256) {
          meta[16 + 2*n256] = e; meta[17 + 2*n256] = off[e] + r; ++n256;
        }
      meta[0] = n256;
      for (int e = 0; e <= EE; ++e) meta[1 + e] = off[e];
    }
    __syncthreads();
    for (int p = tid; p < PP; p += blockDim.x) {
      int e = eidx[p];
      int q = off[e] + atomicAdd(&cur[e], 1);
      plist[q] = p;
      pos[p] = q;
    }
  } else if (b < 1 + 4096) {
    // ---- x -> bf16 (float4 in, ushort4 out) ----
    int i = (b - 1) * 256 + tid;                 // over TT*DD/4
    float4 v = reinterpret_cast<const float4*>(x)[i];
    ushort4 o;
    o.x = f2bf(v.x); o.y = f2bf(v.y); o.z = f2bf(v.z); o.w = f2bf(v.w);
    reinterpret_cast<ushort4*>(xb)[i] = o;
  } else if (b < 1 + 4096 + 8192) {
    // ---- W1 [D][4096] -> w1t [4096][D] per expert; orig grid (64,16,8) ----
    int flat = b - (1 + 4096);
    transpose_tile(W1, w1t, DD, CC1, flat & 63, (flat >> 6) & 15, flat >> 10, t, tid);
  } else {
    // ---- W2 [H][1024] -> w2t [1024][H] per expert; orig grid (16,32,8) ----
    int flat = b - (1 + 4096 + 8192);
    transpose_tile(W2, w2t, HH, DD, flat & 15, (flat >> 4) & 31, flat >> 9, t, tid);
  }
}

// ---------------- GEMM1: up = x @ W1[e], fused GLU + gate, bf16 out (sorted order) ----------
// 256x128 tile (64 h + paired 64 g cols), BK=64, 8 waves (4Mx2N),
// depth-2 prefetch (3 LDS buffers), counted vmcnt(6) + raw s_barrier,
// T2 XOR-swizzle (linear gload_lds dest + pre-swizzled global src + swizzled ds_read).
// K-loop FULLY UNROLLED (trip 14) with As[kt%3] constant indexing.
// grid: (40 row-tiles, 32 col-tiles); block 512
__global__ __launch_bounds__(512) void k_gemm1(
    const unsigned short* __restrict__ xb,     // [T][1024] bf16
    const unsigned short* __restrict__ w1t,    // [E][4096][1024] bf16 ([col][k])
    const float* __restrict__ gates,           // [P] f32
    const int* __restrict__ meta,
    const int* __restrict__ plist,
    unsigned short* __restrict__ abuf)         // [P][2048] bf16
{
  const int nt = meta[0];
  const int tb = blockIdx.x;
  if (tb >= nt) return;
  const int e  = meta[16 + 2*tb];
  const int q0 = meta[17 + 2*tb];
  const int nrows = min(256, meta[2 + e] - q0);
  const int c0 = blockIdx.y * 64;              // h-col base

  __shared__ unsigned short As[3][256 * 64];   // 96 KB
  __shared__ unsigned short Bs[3][128 * 64];   // 48 KB

  const int tid = threadIdx.x;                 // 0..511
  const int wave = tid >> 6, lane = tid & 63;
  const int l15 = lane & 15, l4 = lane >> 4;
  const int wr = wave >> 1, wc = wave & 1;     // 4M x 2N wave grid

  const unsigned short* w1e = w1t + (size_t)e * CC1 * DD;

  const unsigned short* aga[4];
  const unsigned short* bga[2];
#pragma unroll
  for (int i = 0; i < 4; ++i) {
    int c = tid + i * 512;                     // 0..2047
    int row = c >> 3;                          // 0..255
    int ko = ((c & 7) ^ (row & 7)) * 8;
    int r = row < nrows ? row : 0;
    int p = plist[q0 + r];
    aga[i] = xb + (size_t)(p >> 1) * DD + ko;
  }
#pragma unroll
  for (int i = 0; i < 2; ++i) {
    int c = tid + i * 512;                     // 0..1023
    int row = c >> 3;                          // 0..127
    int ko = ((c & 7) ^ (row & 7)) * 8;
    int u = row & 63, wcq = row >> 6;
    int col = (u < 32) ? (c0 + wcq * 32 + u) : (HH + c0 + wcq * 32 + (u - 32));
    bga[i] = w1e + (size_t)col * DD + ko;
  }

  f32x4 acc[4][4];
#pragma unroll
  for (int a = 0; a < 4; ++a)
#pragma unroll
    for (int b = 0; b < 4; ++b) acc[a][b] = (f32x4)0.0f;

  auto stage = [&](int kk, unsigned short* pa, unsigned short* pb) {
#pragma unroll
    for (int i = 0; i < 4; ++i) gload16(aga[i] + kk, pa + (tid + i * 512) * 8);
#pragma unroll
    for (int i = 0; i < 2; ++i) gload16(bga[i] + kk, pb + (tid + i * 512) * 8);
  };

  auto compute_tile = [&](const unsigned short* sa, const unsigned short* sb) {
    const char* A8 = (const char*)sa;
    const char* B8 = (const char*)sb;
#pragma unroll
    for (int ks = 0; ks < 2; ++ks) {
      s16x8 af[4], bfr[4];
#pragma unroll
      for (int rf = 0; rf < 4; ++rf) {
        int row = wr * 64 + rf * 16 + l15;
        af[rf] = *(const s16x8*)(A8 + ((row * 128 + ks * 64 + l4 * 16) ^ ((row & 7) << 4)));
      }
#pragma unroll
      for (int cf = 0; cf < 4; ++cf) {
        int row = wc * 64 + cf * 16 + l15;
        bfr[cf] = *(const s16x8*)(B8 + ((row * 128 + ks * 64 + l4 * 16) ^ ((row & 7) << 4)));
      }
#pragma unroll
      for (int rf = 0; rf < 4; ++rf)
#pragma unroll
        for (int cf = 0; cf < 4; ++cf)
          acc[rf][cf] = __builtin_amdgcn_mfma_f32_16x16x32_bf16(af[rf], bfr[cf], acc[rf][cf], 0, 0, 0);
    }
  };

  stage(0, As[0], Bs[0]);
  stage(64, As[1], Bs[1]);
  VMCNT(6);                                    // tile 0 landed; tile 1 may fly
  __builtin_amdgcn_s_barrier();
  CFENCE();

#pragma unroll
  for (int kt = 0; kt < 14; ++kt) {            // DD/64 - 2; fully unrolled, const indices
    stage((kt + 2) * 64, As[(kt + 2) % 3], Bs[(kt + 2) % 3]);
    compute_tile(As[kt % 3], Bs[kt % 3]);
    VMCNT(6);                                  // all but newest K-tile landed
    __builtin_amdgcn_s_barrier();
    CFENCE();
  }
  compute_tile(As[14 % 3], Bs[14 % 3]);        // tile NT-2
  VMCNT(0);
  __builtin_amdgcn_s_barrier();
  CFENCE();
  compute_tile(As[15 % 3], Bs[15 % 3]);        // tile NT-1

  // Epilogue: a = gelu_exact(h) * (g+1) * gate, bf16.
#pragma unroll
  for (int rf = 0; rf < 4; ++rf) {
#pragma unroll
    for (int i = 0; i < 4; ++i) {
      int r = wr * 64 + rf * 16 + l4 * 4 + i;
      if (r < nrows) {
        int q = q0 + r;
        float gt = gates[plist[q]];
        unsigned short* orow = abuf + (size_t)q * HH + c0 + wc * 32 + l15;
#pragma unroll
        for (int cf = 0; cf < 2; ++cf) {
          float hv = acc[rf][cf][i];
          float gv = acc[rf][cf + 2][i];
          float av = 0.5f * hv * (1.0f + erff(hv * 0.70710678118654752f)) * (gv + 1.0f) * gt;
          orow[cf * 16] = f2bf(av);
        }
      }
    }
  }
}

// ---------------- GEMM2: down_z = a @ W2[e][kz:kz+1024], bf16 partials (K-split 2) --------
// Same engine, same full-unroll treatment (NT=16 -> 14-trip unrolled loop).
// grid: (40 row-tiles, 8 col-tiles of 128, 2 K-halves); block 512
__global__ __launch_bounds__(512) void k_gemm2(
    const unsigned short* __restrict__ abuf,   // [P][2048] bf16
    const unsigned short* __restrict__ w2t,    // [E][1024][2048] bf16 ([col][k])
    const int* __restrict__ meta,
    unsigned short* __restrict__ down)         // [2][P][1024] bf16
{
  const int nt = meta[0];
  const int tb = blockIdx.x;
  if (tb >= nt) return;
  const int e  = meta[16 + 2*tb];
  const int q0 = meta[17 + 2*tb];
  const int nrows = min(256, meta[2 + e] - q0);
  const int c0 = blockIdx.y * 128;
  const int kz = blockIdx.z * (HH / 2);        // K-half base

  __shared__ unsigned short As[3][256 * 64];   // 96 KB
  __shared__ unsigned short Bs[3][128 * 64];   // 48 KB

  const int tid = threadIdx.x;
  const int wave = tid >> 6, lane = tid & 63;
  const int l15 = lane & 15, l4 = lane >> 4;
  const int wr = wave >> 1, wc = wave & 1;

  const unsigned short* w2e = w2t + (size_t)e * DD * HH;

  const unsigned short* aga[4];
  const unsigned short* bga[2];
#pragma unroll
  for (int i = 0; i < 4; ++i) {
    int c = tid + i * 512;
    int row = c >> 3;                          // 0..255
    int ko = ((c & 7) ^ (row & 7)) * 8;
    int r = row < nrows ? row : 0;
    aga[i] = abuf + (size_t)(q0 + r) * HH + kz + ko;
  }
#pragma unroll
  for (int i = 0; i < 2; ++i) {
    int c = tid + i * 512;
    int row = c >> 3;                          // 0..127
    int ko = ((c & 7) ^ (row & 7)) * 8;
    bga[i] = w2e + (size_t)(c0 + row) * HH + kz + ko;
  }

  f32x4 acc[4][4];
#pragma unroll
  for (int a = 0; a < 4; ++a)
#pragma unroll
    for (int b = 0; b < 4; ++b) acc[a][b] = (f32x4)0.0f;

  auto stage = [&](int kk, unsigned short* pa, unsigned short* pb) {
#pragma unroll
    for (int i = 0; i < 4; ++i) gload16(aga[i] + kk, pa + (tid + i * 512) * 8);
#pragma unroll
    for (int i = 0; i < 2; ++i) gload16(bga[i] + kk, pb + (tid + i * 512) * 8);
  };

  auto compute_tile = [&](const unsigned short* sa, const unsigned short* sb) {
    const char* A8 = (const char*)sa;
    const char* B8 = (const char*)sb;
#pragma unroll
    for (int ks = 0; ks < 2; ++ks) {
      s16x8 af[4], bfr[4];
#pragma unroll
      for (int rf = 0; rf < 4; ++rf) {
        int row = wr * 64 + rf * 16 + l15;
        af[rf] = *(const s16x8*)(A8 + ((row * 128 + ks * 64 + l4 * 16) ^ ((row & 7) << 4)));
      }
#pragma unroll
      for (int cf = 0; cf < 4; ++cf) {
        int row = wc * 64 + cf * 16 + l15;
        bfr[cf] = *(const s16x8*)(B8 + ((row * 128 + ks * 64 + l4 * 16) ^ ((row & 7) << 4)));
      }
#pragma unroll
      for (int rf = 0; rf < 4; ++rf)
#pragma unroll
        for (int cf = 0; cf < 4; ++cf)
          acc[rf][cf] = __builtin_amdgcn_mfma_f32_16x16x32_bf16(af[rf], bfr[cf], acc[rf][cf], 0, 0, 0);
    }
  };

  stage(0, As[0], Bs[0]);
  stage(64, As[1], Bs[1]);
  VMCNT(6);
  __builtin_amdgcn_s_barrier();
  CFENCE();

#pragma unroll
  for (int kt = 0; kt < 14; ++kt) {            // (HH/2)/64 - 2; fully unrolled
    stage((kt + 2) * 64, As[(kt + 2) % 3], Bs[(kt + 2) % 3]);
    compute_tile(As[kt % 3], Bs[kt % 3]);
    VMCNT(6);
    __builtin_amdgcn_s_barrier();
    CFENCE();
  }
  compute_tile(As[14 % 3], Bs[14 % 3]);
  VMCNT(0);
  __builtin_amdgcn_s_barrier();
  CFENCE();
  compute_tile(As[15 % 3], Bs[15 % 3]);

  unsigned short* dz = down + (size_t)blockIdx.z * PP * DD;
#pragma unroll
  for (int rf = 0; rf < 4; ++rf) {
#pragma unroll
    for (int i = 0; i < 4; ++i) {
      int r = wr * 64 + rf * 16 + l4 * 4 + i;
      if (r < nrows) {
        int q = q0 + r;
        unsigned short* orow = dz + (size_t)q * DD + c0 + wc * 64 + l15;
#pragma unroll
        for (int cf = 0; cf < 4; ++cf) orow[cf * 16] = f2bf(acc[rf][cf][i]);
      }
    }
  }
}

// ---------------- combine: y[t] = sum over {pair a,b} x {K-half 0,1} of bf16 partials -----
__global__ void k_combine(const unsigned short* __restrict__ down, const int* __restrict__ pos,
                          float* __restrict__ y) {
  int i = blockIdx.x * blockDim.x + threadIdx.x;  // over TT*DD/8
  if (i >= TT * DD / 8) return;
  int t = i >> 7;            // DD/8 = 128 chunks per row
  int c8 = (i & 127) * 8;
  int qa = pos[2 * t], qb = pos[2 * t + 1];
  const unsigned short* d0 = down;
  const unsigned short* d1 = down + (size_t)PP * DD;
  s16x8 va0 = *reinterpret_cast<const s16x8*>(d0 + (size_t)qa * DD + c8);
  s16x8 va1 = *reinterpret_cast<const s16x8*>(d1 + (size_t)qa * DD + c8);
  s16x8 vb0 = *reinterpret_cast<const s16x8*>(d0 + (size_t)qb * DD + c8);
  s16x8 vb1 = *reinterpret_cast<const s16x8*>(d1 + (size_t)qb * DD + c8);
  float o[8];
#pragma unroll
  for (int j = 0; j < 8; ++j)
    o[j] = bf2f((unsigned short)va0[j]) + bf2f((unsigned short)va1[j]) +
           bf2f((unsigned short)vb0[j]) + bf2f((unsigned short)vb1[j]);
  float4* yo = reinterpret_cast<float4*>(y + (size_t)t * DD + c8);
  yo[0] = (float4){o[0], o[1], o[2], o[3]};
  yo[1] = (float4){o[4], o[5], o[6], o[7]};
}

extern "C" void kernel_launch(void* const* d_in, const int* in_sizes, int n_in,
                              void* d_out, int out_size, void* d_ws, size_t ws_size,
                              hipStream_t stream) {
  const float* x  = (const float*)d_in[0];
  const float* ep = (const float*)d_in[1];
  const int*   ei = (const int*)d_in[2];
  const float* W1 = (const float*)d_in[3];
  const float* W2 = (const float*)d_in[4];
  float* y = (float*)d_out;
  char* ws = (char*)d_ws;

  unsigned short* w1t = (unsigned short*)(ws + W1T_OFF);
  unsigned short* w2t = (unsigned short*)(ws + W2T_OFF);
  unsigned short* xb  = (unsigned short*)(ws + XB_OFF);
  unsigned short* ab  = (unsigned short*)(ws + ABUF_OFF);
  unsigned short* down = (unsigned short*)(ws + DOWN_OFF);
  int* meta   = (int*)(ws + META_OFF);
  int* plist  = (int*)(ws + PAIR_OFF);
  int* pos    = (int*)(ws + POS_OFF);

  // fused prep: 1 (route) + 4096 (cvt_x) + 8192 (W1^T) + 4096 (W2^T) blocks
  hipLaunchKernelGGL(k_prep, dim3(1 + 4096 + 8192 + 4096), dim3(256), 0, stream,
                     x, xb, W1, w1t, W2, w2t, ei, meta, plist, pos);
  hipLaunchKernelGGL(k_gemm1, dim3(40, 32), dim3(512), 0, stream,
                     xb, w1t, ep, meta, plist, ab);
  hipLaunchKernelGGL(k_gemm2, dim3(40, 8, 2), dim3(512), 0, stream,
                     ab, w2t, meta, down);
  hipLaunchKernelGGL(k_combine, dim3(TT * DD / 8 / 256), dim3(256), 0, stream,
                     down, pos, y);
}